// Round 2
// baseline (143.455 us; speedup 1.0000x reference)
//
#include <hip/hip_runtime.h>

#define H     300
#define MID   100
#define NN    1024
#define NP1   1025
#define SST   1088   // padded row stride of s2T in floats (1088*4 = 4352 B, 256B-aligned rows)

// ---------------------------------------------------------------------------
// Kernel T: transpose W1 (100 x 600, row-major) -> W1T (600 x 100).
// LDS-tiled so both global read and write are coalesced. 10 blocks, ~2 us.
// ---------------------------------------------------------------------------
__global__ __launch_bounds__(256) void transpose_kernel(
    const float* __restrict__ W1, float* __restrict__ W1T)
{
    __shared__ float tile[MID][65];           // 65 stride breaks bank conflicts
    const int c0 = blockIdx.x * 64;
    const int tid = threadIdx.x;

    for (int idx = tid; idx < MID * 64; idx += 256) {
        const int m = idx >> 6, cc = idx & 63, c = c0 + cc;
        if (c < 2 * H) tile[m][cc] = W1[m * (2 * H) + c];
    }
    __syncthreads();
    for (int idx = tid; idx < 64 * MID; idx += 256) {
        const int cc = idx / MID, m = idx - cc * MID, c = c0 + cc;
        if (c < 2 * H) W1T[c * MID + m] = tile[m][cc];
    }
}

// ---------------------------------------------------------------------------
// Kernel A: fused s1/s2 precompute with coalesced W1T reads.
// Block b handles items i0=2b, i1=2b+1. For item i:
//   s1b[i][m]      = b1[m] + sum_h sent[i][h] * W1T[h][m]        (W1 first half)
//   s2T[m][i+1]    =         sum_h sent[i][h] * W1T[300+h][m]    (W1 second half)
// Each W1T load (coalesced: lanes m consecutive) is reused for 2 items.
// Block 0 also zeroes s2T column 0 (pm[0] = zeros).
// ---------------------------------------------------------------------------
__global__ __launch_bounds__(128) void precompute_kernel(
    const float* __restrict__ sentence,
    const float* __restrict__ W1T,
    const float* __restrict__ b1,
    float* __restrict__ s1b,
    float* __restrict__ s2T)
{
    __shared__ float rA[H];
    __shared__ float rB[H];
    const int tid = threadIdx.x;
    const int i0 = blockIdx.x * 2;
    const int i1 = i0 + 1;

    const float* sA = sentence + (long)i0 * H;
    const float* sB = sentence + (long)i1 * H;
    for (int h = tid; h < H; h += 128) { rA[h] = sA[h]; rB[h] = sB[h]; }
    __syncthreads();

    const int m = tid;
    if (m < MID) {
        float a1A = 0.f, a1B = 0.f, a2A = 0.f, a2B = 0.f;
        #pragma unroll 4
        for (int h = 0; h < H; ++h) {
            const float w1 = W1T[h * MID + m];
            const float w2 = W1T[(H + h) * MID + m];
            const float xA = rA[h], xB = rB[h];
            a1A += w1 * xA; a1B += w1 * xB;
            a2A += w2 * xA; a2B += w2 * xB;
        }
        const float bb = b1[m];
        s1b[i0 * MID + m] = a1A + bb;
        s1b[i1 * MID + m] = a1B + bb;
        s2T[(long)m * SST + (i0 + 1)] = a2A;
        s2T[(long)m * SST + (i1 + 1)] = a2B;
        if (blockIdx.x == 0) s2T[(long)m * SST] = 0.f;
    }
}

// ---------------------------------------------------------------------------
// Kernel B: one block per row i (1024 blocks x 256 threads).
// scores[i][j] = b2 + sum_m W2[m] * sigmoid(s1[i][m] + s2T[m][j])
// sigmoid via pre-scaled a' = s1*(-log2e):  sig = rcp(1 + exp2(fma(x,-log2e,a')))
// Then loss partial -> atomicAdd(out[0]); row softmax -> out[1 + i*1025 + j].
// ---------------------------------------------------------------------------
__global__ __launch_bounds__(256) void main_kernel(
    const float* __restrict__ s1b,
    const float* __restrict__ s2T,
    const float* __restrict__ W2,
    const float* __restrict__ b2,
    const int*   __restrict__ target,
    float* __restrict__ out)
{
    __shared__ float2 aw[MID];     // {s1[m]*(-log2e), W2[m]}
    __shared__ float tmp[MID];     // col-1024 partials
    __shared__ float wred[8];      // per-wave reduction slots
    __shared__ float sROWMAX;
    __shared__ float sINV;

    const int i = blockIdx.x;
    const int tid = threadIdx.x;
    const int lane = tid & 63;
    const int wv = tid >> 6;
    const float NLOG2E = -1.4426950408889634f;
    const float LOG2E  =  1.4426950408889634f;

    if (tid < MID) aw[tid] = make_float2(s1b[i * MID + tid] * NLOG2E, W2[tid]);
    const float b2v = b2[0];
    __syncthreads();

    // ---- main pairwise loop: 4 columns/thread, coalesced 256B-aligned reads ----
    float acc0 = 0.f, acc1 = 0.f, acc2 = 0.f, acc3 = 0.f;
    #pragma unroll 2
    for (int m = 0; m < MID; ++m) {
        const float2 awv = aw[m];
        const float* p = s2T + (long)m * SST;
        const float x0 = p[tid];
        const float x1 = p[tid + 256];
        const float x2 = p[tid + 512];
        const float x3 = p[tid + 768];
        acc0 += awv.y * __builtin_amdgcn_rcpf(1.f + __builtin_amdgcn_exp2f(__builtin_fmaf(x0, NLOG2E, awv.x)));
        acc1 += awv.y * __builtin_amdgcn_rcpf(1.f + __builtin_amdgcn_exp2f(__builtin_fmaf(x1, NLOG2E, awv.x)));
        acc2 += awv.y * __builtin_amdgcn_rcpf(1.f + __builtin_amdgcn_exp2f(__builtin_fmaf(x2, NLOG2E, awv.x)));
        acc3 += awv.y * __builtin_amdgcn_rcpf(1.f + __builtin_amdgcn_exp2f(__builtin_fmaf(x3, NLOG2E, awv.x)));
    }
    const float sc0 = acc0 + b2v;
    const float sc1 = acc1 + b2v;
    const float sc2 = acc2 + b2v;
    const float sc3 = acc3 + b2v;

    // ---- remainder column j = 1024 ----
    if (tid < MID) {
        const float2 awv = aw[tid];
        const float x = s2T[(long)tid * SST + 1024];
        tmp[tid] = awv.y * __builtin_amdgcn_rcpf(1.f + __builtin_amdgcn_exp2f(__builtin_fmaf(x, NLOG2E, awv.x)));
    }
    __syncthreads();
    float sc4 = 0.f;
    if (tid == 0) {
        float s = 0.f;
        #pragma unroll 4
        for (int m = 0; m < MID; ++m) s += tmp[m];
        sc4 = s + b2v;
    }

    // ---- fused loss-sum + row-max reduction (shuffle + 4-slot LDS) ----
    const int tgt = target[i];
    float ls = fabsf(sc0 - ((tid        == tgt) ? 1.f : 0.f))
             + fabsf(sc1 - ((tid + 256  == tgt) ? 1.f : 0.f))
             + fabsf(sc2 - ((tid + 512  == tgt) ? 1.f : 0.f))
             + fabsf(sc3 - ((tid + 768  == tgt) ? 1.f : 0.f));
    float ml = fmaxf(fmaxf(sc0, sc1), fmaxf(sc2, sc3));
    if (tid == 0) {
        ls += fabsf(sc4 - ((1024 == tgt) ? 1.f : 0.f));
        ml = fmaxf(ml, sc4);
    }
    #pragma unroll
    for (int off = 32; off > 0; off >>= 1) {
        ls += __shfl_down(ls, off);
        ml = fmaxf(ml, __shfl_down(ml, off));
    }
    if (lane == 0) { wred[wv] = ls; wred[4 + wv] = ml; }
    __syncthreads();
    if (tid == 0) {
        const float L = wred[0] + wred[1] + wred[2] + wred[3];
        atomicAdd(out, L * (1.0f / ((float)NN * (float)NP1)));
        sROWMAX = fmaxf(fmaxf(wred[4], wred[5]), fmaxf(wred[6], wred[7]));
    }
    __syncthreads();
    const float rowmax = sROWMAX;

    // ---- exp + sum ----
    const float e0 = __builtin_amdgcn_exp2f((sc0 - rowmax) * LOG2E);
    const float e1 = __builtin_amdgcn_exp2f((sc1 - rowmax) * LOG2E);
    const float e2 = __builtin_amdgcn_exp2f((sc2 - rowmax) * LOG2E);
    const float e3 = __builtin_amdgcn_exp2f((sc3 - rowmax) * LOG2E);
    float e4 = 0.f;
    if (tid == 0) e4 = __builtin_amdgcn_exp2f((sc4 - rowmax) * LOG2E);
    float es = e0 + e1 + e2 + e3 + e4;
    #pragma unroll
    for (int off = 32; off > 0; off >>= 1) es += __shfl_down(es, off);
    if (lane == 0) wred[wv] = es;
    __syncthreads();
    if (tid == 0) sINV = 1.0f / (wred[0] + wred[1] + wred[2] + wred[3]);
    __syncthreads();
    const float inv = sINV;

    // ---- write softmax row ----
    float* orow = out + 1 + (long)i * NP1;
    orow[tid]       = e0 * inv;
    orow[tid + 256] = e1 * inv;
    orow[tid + 512] = e2 * inv;
    orow[tid + 768] = e3 * inv;
    if (tid == 0) orow[1024] = e4 * inv;
}

extern "C" void kernel_launch(void* const* d_in, const int* in_sizes, int n_in,
                              void* d_out, int out_size, void* d_ws, size_t ws_size,
                              hipStream_t stream) {
    const float* sentence = (const float*)d_in[0];
    const int*   target   = (const int*)  d_in[1];
    const float* W1       = (const float*)d_in[2];
    const float* b1       = (const float*)d_in[3];
    const float* W2       = (const float*)d_in[4];
    const float* b2       = (const float*)d_in[5];
    float* out = (float*)d_out;

    float* s1b = (float*)d_ws;                 // 1024*100 floats
    float* s2T = s1b + NN * MID;               // 100*1088 floats (padded stride)
    float* W1T = s2T + MID * SST;              // 600*100 floats

    // zero the loss accumulator (d_out is re-poisoned to 0xAA before every launch)
    hipMemsetAsync(d_out, 0, sizeof(float), stream);

    transpose_kernel<<<(2 * H + 63) / 64, 256, 0, stream>>>(W1, W1T);
    precompute_kernel<<<NN / 2, 128, 0, stream>>>(sentence, W1T, b1, s1b, s2T);
    main_kernel<<<NN, 256, 0, stream>>>(s1b, s2T, W2, b2, target, out);
}

// Round 3
// 131.650 us; speedup vs baseline: 1.0897x; 1.0897x over previous
//
#include <hip/hip_runtime.h>

#define H     300
#define MID   100
#define NN    1024
#define NP1   1025
#define SST   1088   // padded row stride of s2T in floats (4352 B, 256B-aligned rows)

static __device__ __forceinline__ float sig_pre(float x, float apre) {
    // sigmoid(s1+x) with apre = s1 * (-log2e):  rcp(1 + exp2(fma(x, -log2e, apre)))
    const float NL = -1.4426950408889634f;
    return __builtin_amdgcn_rcpf(1.0f + __builtin_amdgcn_exp2f(__builtin_fmaf(x, NL, apre)));
}

// ---------------------------------------------------------------------------
// Kernel T: transpose W1 (100 x 600) -> W1T (600 x 100), LDS-tiled.
// ---------------------------------------------------------------------------
__global__ __launch_bounds__(256) void transpose_kernel(
    const float* __restrict__ W1, float* __restrict__ W1T)
{
    __shared__ float tile[MID][65];
    const int c0 = blockIdx.x * 64;
    const int tid = threadIdx.x;
    for (int idx = tid; idx < MID * 64; idx += 256) {
        const int m = idx >> 6, cc = idx & 63, c = c0 + cc;
        if (c < 2 * H) tile[m][cc] = W1[m * (2 * H) + c];
    }
    __syncthreads();
    for (int idx = tid; idx < 64 * MID; idx += 256) {
        const int cc = idx / MID, m = idx - cc * MID, c = c0 + cc;
        if (c < 2 * H) W1T[c * MID + m] = tile[m][cc];
    }
}

// ---------------------------------------------------------------------------
// Kernel A: fused s1/s2 precompute, coalesced W1T reads, 2 items per block.
// ---------------------------------------------------------------------------
__global__ __launch_bounds__(128) void precompute_kernel(
    const float* __restrict__ sentence,
    const float* __restrict__ W1T,
    const float* __restrict__ b1,
    float* __restrict__ s1b,
    float* __restrict__ s2T)
{
    __shared__ float rA[H];
    __shared__ float rB[H];
    const int tid = threadIdx.x;
    const int i0 = blockIdx.x * 2;
    const int i1 = i0 + 1;

    const float* sA = sentence + (long)i0 * H;
    const float* sB = sentence + (long)i1 * H;
    for (int h = tid; h < H; h += 128) { rA[h] = sA[h]; rB[h] = sB[h]; }
    __syncthreads();

    const int m = tid;
    if (m < MID) {
        float a1A = 0.f, a1B = 0.f, a2A = 0.f, a2B = 0.f;
        #pragma unroll 4
        for (int h = 0; h < H; ++h) {
            const float w1 = W1T[h * MID + m];
            const float w2 = W1T[(H + h) * MID + m];
            const float xA = rA[h], xB = rB[h];
            a1A += w1 * xA; a1B += w1 * xB;
            a2A += w2 * xA; a2B += w2 * xB;
        }
        const float bb = b1[m];
        s1b[i0 * MID + m] = a1A + bb;
        s1b[i1 * MID + m] = a1B + bb;
        s2T[(long)m * SST + (i0 + 1)] = a2A;
        s2T[(long)m * SST + (i1 + 1)] = a2B;
        if (blockIdx.x == 0) s2T[(long)m * SST] = 0.f;
    }
}

// ---------------------------------------------------------------------------
// Kernel B: 512 blocks x 256 threads; block b handles rows iA=2b, iB=2b+1.
// Thread handles 4 consecutive columns j = 4*tid..4*tid+3 via ONE float4 load
// per m, reused for both rows (8 sigmoids per load). Distance-2 SW pipeline.
// ---------------------------------------------------------------------------
__global__ __launch_bounds__(256) void main_kernel(
    const float* __restrict__ s1b,
    const float* __restrict__ s2T,
    const float* __restrict__ W2,
    const float* __restrict__ b2,
    const int*   __restrict__ target,
    float* __restrict__ out)
{
    __shared__ float4 aw4[MID];        // {s1A[m]*-log2e, s1B[m]*-log2e, W2[m], 0}
    __shared__ float tmpA[MID], tmpB[MID];
    __shared__ float r1[4], r2[4], r3[4];
    __shared__ float bc[4];            // rowmaxA, rowmaxB, invA, invB
    __shared__ float sc4sh[2];

    const int iA = blockIdx.x * 2, iB = iA + 1;
    const int tid = threadIdx.x;
    const int lane = tid & 63, wv = tid >> 6;
    const float NL  = -1.4426950408889634f;
    const float L2E =  1.4426950408889634f;

    if (tid < MID)
        aw4[tid] = make_float4(s1b[iA * MID + tid] * NL,
                               s1b[iB * MID + tid] * NL,
                               W2[tid], 0.f);
    const float b2v = b2[0];
    __syncthreads();

    const long colbase = (long)(tid << 2);
    #define LDX(m) (*(const float4*)(s2T + (long)(m) * SST + colbase))

    float aA0 = 0.f, aA1 = 0.f, aA2 = 0.f, aA3 = 0.f;
    float aB0 = 0.f, aB1 = 0.f, aB2 = 0.f, aB3 = 0.f;

    #define BODY(W, X)                                   \
        do {                                             \
            aA0 += (W).z * sig_pre((X).x, (W).x);        \
            aA1 += (W).z * sig_pre((X).y, (W).x);        \
            aA2 += (W).z * sig_pre((X).z, (W).x);        \
            aA3 += (W).z * sig_pre((X).w, (W).x);        \
            aB0 += (W).z * sig_pre((X).x, (W).y);        \
            aB1 += (W).z * sig_pre((X).y, (W).y);        \
            aB2 += (W).z * sig_pre((X).z, (W).y);        \
            aB3 += (W).z * sig_pre((X).w, (W).y);        \
        } while (0)

    float4 x0 = LDX(0), x1 = LDX(1);
    #pragma unroll 2
    for (int m = 0; m < MID - 2; ++m) {
        float4 xn = LDX(m + 2);
        float4 w  = aw4[m];
        BODY(w, x0);
        x0 = x1; x1 = xn;
    }
    {
        float4 w = aw4[MID - 2]; BODY(w, x0);
        w = aw4[MID - 1];        BODY(w, x1);
    }

    const float scA0 = aA0 + b2v, scA1 = aA1 + b2v, scA2 = aA2 + b2v, scA3 = aA3 + b2v;
    const float scB0 = aB0 + b2v, scB1 = aB1 + b2v, scB2 = aB2 + b2v, scB3 = aB3 + b2v;

    // ---- remainder column j = 1024 (both rows) ----
    if (tid < MID) {
        const float4 w = aw4[tid];
        const float x = s2T[(long)tid * SST + 1024];
        tmpA[tid] = w.z * sig_pre(x, w.x);
        tmpB[tid] = w.z * sig_pre(x, w.y);
    }
    __syncthreads();
    if (wv == 0) {
        float v = tmpA[lane] + ((lane < MID - 64) ? tmpA[lane + 64] : 0.f);
        #pragma unroll
        for (int off = 32; off > 0; off >>= 1) v += __shfl_down(v, off);
        if (lane == 0) sc4sh[0] = v + b2v;
    } else if (wv == 1) {
        float v = tmpB[lane] + ((lane < MID - 64) ? tmpB[lane + 64] : 0.f);
        #pragma unroll
        for (int off = 32; off > 0; off >>= 1) v += __shfl_down(v, off);
        if (lane == 0) sc4sh[1] = v + b2v;
    }
    __syncthreads();
    const float sc4A = sc4sh[0];
    const float sc4B = sc4sh[1];

    // ---- loss + row-max (wave shuffle, then 4-slot LDS combine) ----
    const int tgtA = target[iA], tgtB = target[iB];
    const int j0 = tid << 2;
    float ls = fabsf(scA0 - ((j0     == tgtA) ? 1.f : 0.f))
             + fabsf(scA1 - ((j0 + 1 == tgtA) ? 1.f : 0.f))
             + fabsf(scA2 - ((j0 + 2 == tgtA) ? 1.f : 0.f))
             + fabsf(scA3 - ((j0 + 3 == tgtA) ? 1.f : 0.f))
             + fabsf(scB0 - ((j0     == tgtB) ? 1.f : 0.f))
             + fabsf(scB1 - ((j0 + 1 == tgtB) ? 1.f : 0.f))
             + fabsf(scB2 - ((j0 + 2 == tgtB) ? 1.f : 0.f))
             + fabsf(scB3 - ((j0 + 3 == tgtB) ? 1.f : 0.f));
    float mA = fmaxf(fmaxf(scA0, scA1), fmaxf(scA2, scA3));
    float mB = fmaxf(fmaxf(scB0, scB1), fmaxf(scB2, scB3));
    if (tid == 0) {
        ls += fabsf(sc4A - ((1024 == tgtA) ? 1.f : 0.f))
            + fabsf(sc4B - ((1024 == tgtB) ? 1.f : 0.f));
        mA = fmaxf(mA, sc4A);
        mB = fmaxf(mB, sc4B);
    }
    #pragma unroll
    for (int off = 32; off > 0; off >>= 1) {
        ls += __shfl_down(ls, off);
        mA = fmaxf(mA, __shfl_down(mA, off));
        mB = fmaxf(mB, __shfl_down(mB, off));
    }
    if (lane == 0) { r1[wv] = ls; r2[wv] = mA; r3[wv] = mB; }
    __syncthreads();
    if (tid == 0) {
        atomicAdd(out, (r1[0] + r1[1] + r1[2] + r1[3]) * (1.0f / ((float)NN * (float)NP1)));
        bc[0] = fmaxf(fmaxf(r2[0], r2[1]), fmaxf(r2[2], r2[3]));
        bc[1] = fmaxf(fmaxf(r3[0], r3[1]), fmaxf(r3[2], r3[3]));
    }
    __syncthreads();
    const float rmA = bc[0], rmB = bc[1];

    // ---- exp + sum per row ----
    const float eA0 = __builtin_amdgcn_exp2f((scA0 - rmA) * L2E);
    const float eA1 = __builtin_amdgcn_exp2f((scA1 - rmA) * L2E);
    const float eA2 = __builtin_amdgcn_exp2f((scA2 - rmA) * L2E);
    const float eA3 = __builtin_amdgcn_exp2f((scA3 - rmA) * L2E);
    const float eB0 = __builtin_amdgcn_exp2f((scB0 - rmB) * L2E);
    const float eB1 = __builtin_amdgcn_exp2f((scB1 - rmB) * L2E);
    const float eB2 = __builtin_amdgcn_exp2f((scB2 - rmB) * L2E);
    const float eB3 = __builtin_amdgcn_exp2f((scB3 - rmB) * L2E);
    float e4A = 0.f, e4B = 0.f;
    if (tid == 0) {
        e4A = __builtin_amdgcn_exp2f((sc4A - rmA) * L2E);
        e4B = __builtin_amdgcn_exp2f((sc4B - rmB) * L2E);
    }
    float esA = eA0 + eA1 + eA2 + eA3 + e4A;
    float esB = eB0 + eB1 + eB2 + eB3 + e4B;
    #pragma unroll
    for (int off = 32; off > 0; off >>= 1) {
        esA += __shfl_down(esA, off);
        esB += __shfl_down(esB, off);
    }
    if (lane == 0) { r1[wv] = esA; r2[wv] = esB; }
    __syncthreads();
    if (tid == 0) {
        bc[2] = 1.0f / (r1[0] + r1[1] + r1[2] + r1[3]);
        bc[3] = 1.0f / (r2[0] + r2[1] + r2[2] + r2[3]);
    }
    __syncthreads();
    const float invA = bc[2], invB = bc[3];

    // ---- write softmax rows ----
    float* orowA = out + 1 + (long)iA * NP1;
    float* orowB = out + 1 + (long)iB * NP1;
    orowA[j0]     = eA0 * invA;
    orowA[j0 + 1] = eA1 * invA;
    orowA[j0 + 2] = eA2 * invA;
    orowA[j0 + 3] = eA3 * invA;
    orowB[j0]     = eB0 * invB;
    orowB[j0 + 1] = eB1 * invB;
    orowB[j0 + 2] = eB2 * invB;
    orowB[j0 + 3] = eB3 * invB;
    if (tid == 0) {
        orowA[1024] = e4A * invA;
        orowB[1024] = e4B * invB;
    }
    #undef BODY
    #undef LDX
}

extern "C" void kernel_launch(void* const* d_in, const int* in_sizes, int n_in,
                              void* d_out, int out_size, void* d_ws, size_t ws_size,
                              hipStream_t stream) {
    const float* sentence = (const float*)d_in[0];
    const int*   target   = (const int*)  d_in[1];
    const float* W1       = (const float*)d_in[2];
    const float* b1       = (const float*)d_in[3];
    const float* W2       = (const float*)d_in[4];
    const float* b2       = (const float*)d_in[5];
    float* out = (float*)d_out;

    float* s1b = (float*)d_ws;                 // 1024*100
    float* s2T = s1b + NN * MID;               // 100*1088 (padded stride)
    float* W1T = s2T + MID * SST;              // 600*100

    hipMemsetAsync(d_out, 0, sizeof(float), stream);

    transpose_kernel<<<(2 * H + 63) / 64, 256, 0, stream>>>(W1, W1T);
    precompute_kernel<<<NN / 2, 128, 0, stream>>>(sentence, W1T, b1, s1b, s2T);
    main_kernel<<<NN / 2, 256, 0, stream>>>(s1b, s2T, W2, b2, target, out);
}